// Round 9
// baseline (810.670 us; speedup 1.0000x reference)
//
#include <hip/hip_runtime.h>

#define L_IMG 12
#define BATCH 64
#define NCLS  1000
#define DIM   512
#define NTM   96
#define SCALEF 0.044194173824159216f   // 1/sqrt(512)

typedef __attribute__((ext_vector_type(8))) short bf16x8;
typedef __attribute__((ext_vector_type(4))) float f32x4;

// ---------- bf16 helpers ----------
__device__ __forceinline__ float bf2f(unsigned short u) {
    return __uint_as_float(((unsigned int)u) << 16);
}
__device__ __forceinline__ unsigned short f2bf(float f) {
    unsigned int u = __float_as_uint(f);
    u += 0x7FFFu + ((u >> 16) & 1u);
    return (unsigned short)(u >> 16);
}
__device__ __forceinline__ void storeo(float* p, float v) { *p = v; }
__device__ __forceinline__ void storeo(unsigned short* p, float v) { *p = f2bf(v); }

// XOR-swizzled LDS offset (shorts) for [row][32-short] tiles: 16B unit u ^= (row>>1)&3.
__device__ __forceinline__ int swz(int row, int u) {
    return (row << 5) + ((u ^ ((row >> 1) & 3)) << 3);
}

// async global->LDS, 16 B per lane; LDS dest = wave-uniform base + lane*16 (linear).
// Swizzle achieved by inverse-permuting the per-lane GLOBAL source (rule #21).
__device__ __forceinline__ void gload16(const unsigned short* g, unsigned short* l) {
    __builtin_amdgcn_global_load_lds(
        (const __attribute__((address_space(1))) void*)g,
        (__attribute__((address_space(3))) void*)l, 16, 0, 0);
}

// ---------- fp32 -> bf16 convert (n multiple of 4) ----------
__global__ __launch_bounds__(256)
void f2bf_kernel(const float* __restrict__ in, unsigned short* __restrict__ out, int n)
{
    int i = (blockIdx.x * 256 + threadIdx.x) * 4;
    if (i < n) {
        float4 v = *(const float4*)(in + i);
        ushort4 o;
        o.x = f2bf(v.x); o.y = f2bf(v.y); o.z = f2bf(v.z); o.w = f2bf(v.w);
        *(ushort4*)(out + i) = o;
    }
}

// ---------- Wvo[d,k] = sum_e cow[d,e]*cWv[e,k] (bf16), bvo[d] = cow[d,:].cbv + cob[d] ----------
__global__ __launch_bounds__(256)
void fold_wvo(const float* __restrict__ cow, const float* __restrict__ cWv,
              const float* __restrict__ cbv, const float* __restrict__ cob,
              unsigned short* __restrict__ Wvob, float* __restrict__ bvo)
{
    __shared__ float crow[DIM];
    __shared__ float red[256];
    const int d = blockIdx.x, t = threadIdx.x;
    float c0 = cow[d * DIM + t], c1 = cow[d * DIM + t + 256];
    crow[t] = c0; crow[t + 256] = c1;
    red[t] = c0 * cbv[t] + c1 * cbv[t + 256];
    __syncthreads();
    for (int s = 128; s > 0; s >>= 1) {
        if (t < s) red[t] += red[t + s];
        __syncthreads();
    }
    if (t == 0) bvo[d] = red[0] + cob[d];
    float a0 = 0.f, a1 = 0.f;
    for (int e = 0; e < DIM; e++) {
        float ce = crow[e];
        a0 += ce * cWv[e * DIM + t];
        a1 += ce * cWv[e * DIM + t + 256];
    }
    Wvob[d * DIM + t]       = f2bf(a0);
    Wvob[d * DIM + t + 256] = f2bf(a1);
}

// ---------- small fp32 tiled GEMM: C[M,N] = (A[M,K] @ W[N,K]^T + bias) * scale ----------
#define BKT 32
#define LDT 68
__global__ __launch_bounds__(256)
void gemm_bt_f32(const float* __restrict__ A, const float* __restrict__ W,
                 const float* __restrict__ bias, float* __restrict__ Co,
                 int M, int N, int K, float out_scale)
{
    __shared__ float As[BKT * LDT];
    __shared__ float Ws[BKT * LDT];
    const int tid = threadIdx.x;
    const int m0 = blockIdx.y << 6, n0 = blockIdx.x << 6;
    const int tx = tid & 15, ty = tid >> 4;
    float acc[4][4] = {};
    for (int k0 = 0; k0 < K; k0 += BKT) {
        #pragma unroll
        for (int i = 0; i < 2; i++) {
            int slot = tid + (i << 8);
            int r = slot >> 3, kq = slot & 7;
            float4 v = *(const float4*)(A + (size_t)(m0 + r) * K + k0 + (kq << 2));
            As[(kq*4+0)*LDT + r] = v.x; As[(kq*4+1)*LDT + r] = v.y;
            As[(kq*4+2)*LDT + r] = v.z; As[(kq*4+3)*LDT + r] = v.w;
            float4 w = *(const float4*)(W + (size_t)(n0 + r) * K + k0 + (kq << 2));
            Ws[(kq*4+0)*LDT + r] = w.x; Ws[(kq*4+1)*LDT + r] = w.y;
            Ws[(kq*4+2)*LDT + r] = w.z; Ws[(kq*4+3)*LDT + r] = w.w;
        }
        __syncthreads();
        #pragma unroll
        for (int kk = 0; kk < BKT; kk++) {
            float4 a = *(const float4*)(As + kk*LDT + ty*4);
            float4 w = *(const float4*)(Ws + kk*LDT + tx*4);
            acc[0][0] += a.x*w.x; acc[0][1] += a.x*w.y; acc[0][2] += a.x*w.z; acc[0][3] += a.x*w.w;
            acc[1][0] += a.y*w.x; acc[1][1] += a.y*w.y; acc[1][2] += a.y*w.z; acc[1][3] += a.y*w.w;
            acc[2][0] += a.z*w.x; acc[2][1] += a.z*w.y; acc[2][2] += a.z*w.z; acc[2][3] += a.z*w.w;
            acc[3][0] += a.w*w.x; acc[3][1] += a.w*w.y; acc[3][2] += a.w*w.z; acc[3][3] += a.w*w.w;
        }
        __syncthreads();
    }
    #pragma unroll
    for (int i = 0; i < 4; i++) {
        int mr = m0 + ty*4 + i;
        #pragma unroll
        for (int j = 0; j < 4; j++) {
            int n = n0 + tx*4 + j;
            float v = acc[i][j];
            if (bias) v += bias[n];
            Co[(size_t)mr * N + n] = v * out_scale;
        }
    }
}

// ---------- small fp32 GEMM, B NOT transposed: C[M,N] = A[M,K] @ W[K,N] ----------
__global__ __launch_bounds__(256)
void gemm_nt_f32(const float* __restrict__ A, const float* __restrict__ W,
                 float* __restrict__ Co, int M, int N, int K)
{
    __shared__ float As[BKT * LDT];
    __shared__ float Ws[BKT * LDT];
    const int tid = threadIdx.x;
    const int m0 = blockIdx.y << 6, n0 = blockIdx.x << 6;
    const int tx = tid & 15, ty = tid >> 4;
    float acc[4][4] = {};
    for (int k0 = 0; k0 < K; k0 += BKT) {
        #pragma unroll
        for (int i = 0; i < 2; i++) {
            int slot = tid + (i << 8);
            int r = slot >> 3, kq = slot & 7;
            float4 v = *(const float4*)(A + (size_t)(m0 + r) * K + k0 + (kq << 2));
            As[(kq*4+0)*LDT + r] = v.x; As[(kq*4+1)*LDT + r] = v.y;
            As[(kq*4+2)*LDT + r] = v.z; As[(kq*4+3)*LDT + r] = v.w;
            int kr = slot >> 4, c4 = slot & 15;
            *(float4*)(Ws + kr*LDT + c4*4) =
                *(const float4*)(W + (size_t)(k0 + kr) * N + n0 + (c4 << 2));
        }
        __syncthreads();
        #pragma unroll
        for (int kk = 0; kk < BKT; kk++) {
            float4 a = *(const float4*)(As + kk*LDT + ty*4);
            float4 w = *(const float4*)(Ws + kk*LDT + tx*4);
            acc[0][0] += a.x*w.x; acc[0][1] += a.x*w.y; acc[0][2] += a.x*w.z; acc[0][3] += a.x*w.w;
            acc[1][0] += a.y*w.x; acc[1][1] += a.y*w.y; acc[1][2] += a.y*w.z; acc[1][3] += a.y*w.w;
            acc[2][0] += a.z*w.x; acc[2][1] += a.z*w.y; acc[2][2] += a.z*w.z; acc[2][3] += a.z*w.w;
            acc[3][0] += a.w*w.x; acc[3][1] += a.w*w.y; acc[3][2] += a.w*w.z; acc[3][3] += a.w*w.w;
        }
        __syncthreads();
    }
    #pragma unroll
    for (int i = 0; i < 4; i++) {
        int mr = m0 + ty*4 + i;
        #pragma unroll
        for (int j = 0; j < 4; j++)
            Co[(size_t)mr * N + n0 + tx*4 + j] = acc[i][j];
    }
}

// ---------- self-attention over the 12-layer axis, one block per batch ----------
__global__ __launch_bounds__(256)
void attn_kernel(const float* __restrict__ qkv, float* __restrict__ ao)
{
    __shared__ float lq[L_IMG * DIM];
    __shared__ float lk[L_IMG * DIM];
    __shared__ float sc[L_IMG * L_IMG];
    __shared__ float sa[L_IMG * L_IMG];
    const int b = blockIdx.x, tid = threadIdx.x;
    for (int i = 0; i < 6; i++) {
        int slot = tid + (i << 8);
        int l = slot >> 7, e4 = slot & 127;
        const float* row = qkv + (size_t)(l * BATCH + b) * 1536;
        *(float4*)(lq + l*DIM + e4*4) = *(const float4*)(row + e4*4);
        *(float4*)(lk + l*DIM + e4*4) = *(const float4*)(row + DIM + e4*4);
    }
    __syncthreads();
    if (tid < 144) {
        int l = tid / 12, m = tid % 12;
        float a = 0.f;
        for (int d4 = 0; d4 < 128; d4++) {
            float4 q = *(const float4*)(lq + l*DIM + d4*4);
            float4 k = *(const float4*)(lk + m*DIM + d4*4);
            a += q.x*k.x + q.y*k.y + q.z*k.z + q.w*k.w;
        }
        sc[tid] = a * SCALEF;
    }
    __syncthreads();
    if (tid < 12) {
        float mx = -1e30f;
        for (int m = 0; m < 12; m++) mx = fmaxf(mx, sc[tid*12 + m]);
        float e[12], s = 0.f;
        for (int m = 0; m < 12; m++) { e[m] = __expf(sc[tid*12 + m] - mx); s += e[m]; }
        float inv = 1.f / s;
        for (int m = 0; m < 12; m++) sa[tid*12 + m] = e[m] * inv;
    }
    __syncthreads();
    for (int i = 0; i < 2; i++) {
        int e = tid + (i << 8);
        float vv[12];
        #pragma unroll
        for (int m = 0; m < 12; m++)
            vv[m] = qkv[(size_t)(m * BATCH + b) * 1536 + 1024 + e];
        #pragma unroll
        for (int l = 0; l < 12; l++) {
            float a = 0.f;
            #pragma unroll
            for (int m = 0; m < 12; m++) a += sa[l*12 + m] * vv[m];
            ao[(size_t)(l * BATCH + b) * DIM + e] = a;
        }
    }
}

// ---------- normalize image features (xs layer 11) ----------
__global__ __launch_bounds__(256)
void img_kernel(const float* __restrict__ xs, float* __restrict__ imgn)
{
    __shared__ float red[256];
    const int b = blockIdx.x, tid = threadIdx.x;
    const float* row = xs + (size_t)(11 * BATCH + b) * DIM;
    float v0 = row[tid], v1 = row[tid + 256];
    red[tid] = v0*v0 + v1*v1;
    __syncthreads();
    for (int s = 128; s > 0; s >>= 1) {
        if (tid < s) red[tid] += red[tid + s];
        __syncthreads();
    }
    float inv = rsqrtf(red[0]);
    imgn[b*DIM + tid]       = v0 * inv;
    imgn[b*DIM + tid + 256] = v1 * inv;
}

// ---------- q2k fp32 [12,64,512] -> q2pk bf16 [64*12, 512] PACKED (row = b*12+l) ----------
__global__ __launch_bounds__(256)
void build_q2p(const float* __restrict__ q2s, unsigned short* __restrict__ q2pk)
{
    const int l = blockIdx.x, b = blockIdx.y, t = threadIdx.x;
    int d0 = t * 2;
    float2 v = *(const float2*)(q2s + (size_t)(l * BATCH + b) * DIM + d0);
    unsigned int o = (unsigned int)f2bf(v.x) | ((unsigned int)f2bf(v.y) << 16);
    ((unsigned int*)q2pk)[(size_t)(b * 12 + l) * 256 + t] = o;
}

// ---------- MFMA GEMM: C[M,N] = A[M,K]@W[N,K]^T + bias ; 128x128 tile, BK=32 ----------
// Async global_load_lds staging, double-buffered. Optional fused n2: per-column
// sum of v^2 (fp32, pre-rounding), shfl-reduced across row-groups, global atomics.
// Row index m = b*NCLS + c; a 128-row tile straddles at most one b-boundary.
template<typename OutT>
__global__ __launch_bounds__(256, 4)
void gemm_mfma(const unsigned short* __restrict__ A, const unsigned short* __restrict__ W,
               const float* __restrict__ bias, OutT* __restrict__ Co,
               int M, int N, float scale, float* __restrict__ n2)
{
    const int K = DIM;
    __shared__ __align__(16) unsigned short AsBuf[2][128 * 32];
    __shared__ __align__(16) unsigned short WsBuf[2][128 * 32];
    const int m0 = blockIdx.y << 7, n0 = blockIdx.x << 7;
    const int tid = threadIdx.x;
    const int w = tid >> 6, lane = tid & 63;
    const int mt0 = (w & 1) * 4, nt0 = (w >> 1) * 4;
    const int r16 = lane & 15, kq = lane >> 4;
    const int row0 = (w << 5) + (lane >> 2), row1 = row0 + 16;
    const int sc0 = ((lane & 3) ^ ((row0 >> 1) & 3)) << 3;
    const int sc1 = ((lane & 3) ^ ((row1 >> 1) & 3)) << 3;
    const unsigned short* gA0 = A + (size_t)(m0 + row0) * K + sc0;
    const unsigned short* gA1 = A + (size_t)(m0 + row1) * K + sc1;
    const unsigned short* gW0 = W + (size_t)(n0 + row0) * K + sc0;
    const unsigned short* gW1 = W + (size_t)(n0 + row1) * K + sc1;
    const int lw = w << 10;
    int offa[4], offb[4];
    #pragma unroll
    for (int i = 0; i < 4; i++) {
        offa[i] = swz((mt0 + i) * 16 + r16, kq);
        offb[i] = swz((nt0 + i) * 16 + r16, kq);
    }
    f32x4 acc[4][4] = {};

    gload16(gA0, AsBuf[0] + lw);
    gload16(gA1, AsBuf[0] + lw + 512);
    gload16(gW0, WsBuf[0] + lw);
    gload16(gW1, WsBuf[0] + lw + 512);
    __syncthreads();

    #pragma unroll
    for (int t = 0; t < 16; t++) {
        const int cur = t & 1, nxt = cur ^ 1;
        if (t < 15) {
            const int ko = (t + 1) << 5;
            gload16(gA0 + ko, AsBuf[nxt] + lw);
            gload16(gA1 + ko, AsBuf[nxt] + lw + 512);
            gload16(gW0 + ko, WsBuf[nxt] + lw);
            gload16(gW1 + ko, WsBuf[nxt] + lw + 512);
        }
        bf16x8 af[4], bfr[4];
        #pragma unroll
        for (int i = 0; i < 4; i++) {
            af[i]  = *(const bf16x8*)(AsBuf[cur] + offa[i]);
            bfr[i] = *(const bf16x8*)(WsBuf[cur] + offb[i]);
        }
        #pragma unroll
        for (int i = 0; i < 4; i++)
            #pragma unroll
            for (int j = 0; j < 4; j++)
                acc[i][j] = __builtin_amdgcn_mfma_f32_16x16x32_bf16(af[i], bfr[j], acc[i][j], 0, 0, 0);
        if (t < 15) __syncthreads();
    }
    const int rbase = (lane >> 4) * 4;
    const int b0 = m0 / NCLS;
    const int splitrow = (b0 + 1) * NCLS;
    #pragma unroll
    for (int j = 0; j < 4; j++) {
        int gcol = n0 + (nt0 + j) * 16 + r16;
        float bv = bias ? bias[gcol] : 0.f;
        float s0 = 0.f, s1 = 0.f;
        #pragma unroll
        for (int i = 0; i < 4; i++)
            #pragma unroll
            for (int r = 0; r < 4; r++) {
                int grow = m0 + (mt0 + i) * 16 + rbase + r;
                float v = acc[i][j][r] * scale + bv;
                storeo(Co + (size_t)grow * N + gcol, v);
                if (n2) { if (grow < splitrow) s0 += v * v; else s1 += v * v; }
            }
        if (n2) {
            s0 += __shfl_xor(s0, 16, 64); s0 += __shfl_xor(s0, 32, 64);
            s1 += __shfl_xor(s1, 16, 64); s1 += __shfl_xor(s1, 32, 64);
            if (lane < 16) {
                atomicAdd(&n2[(size_t)b0 * N + gcol], s0);
                if (splitrow < m0 + 128) atomicAdd(&n2[(size_t)(b0 + 1) * N + gcol], s1);
            }
        }
    }
}

// ---------- fused scores + softmax(m) + sum_l: one block = (class c, 16 batches) ----------
// PACKED queries (row = b*12 + l, no padding): block = 192 rows, wave = 48 rows x 96 cols,
// acc[3][6] (18 MFMA / 9 staging issues per wave per iter). Each in-lane 4-row group
// 4(4i+g)..+3 lies inside one batch (base mod 12 in {0,4,8}); batch = (4i+g)/3.
// Sum_l via per-wave LDS scatter (aliased onto dead AsBuf[0]); no pad masking.
// K-source is tfeb directly (cWk folded into query; k-bias cancels in softmax).
// XCD-grouped 1-D grid (4 bg-blocks of a class share an XCD).
__global__ __launch_bounds__(256, 4)
void fused_scores(const unsigned short* __restrict__ q2pk, const unsigned short* __restrict__ k2,
                  float* __restrict__ wout)
{
    __shared__ __align__(16) unsigned short AsBuf[2][192 * 32];  // 2 x 12288 B
    __shared__ __align__(16) unsigned short KsBuf[2][96 * 32];   // 2 x  6144 B
    const int bid = blockIdx.x;
    const int g8 = bid >> 5, r = bid & 31;
    const int c = g8 * 8 + (r & 7), bg = r >> 3;    // bg in 0..3, 16 batches each
    const int tid = threadIdx.x;
    const int m0 = bg * 192;
    const int w = tid >> 6, lane = tid & 63;
    const int r16 = lane & 15, kq = lane >> 4;
    const size_t kb = (size_t)c * NTM * DIM;
    const int arow = lane >> 2, aun = lane & 3;
    // A staging: wave w stages rows w*48 .. w*48+47 (3 issues x 16 rows)
    const unsigned short* gAs[3];
    #pragma unroll
    for (int s = 0; s < 3; s++) {
        int rw = w * 48 + (s << 4) + arow;
        int scx = (aun ^ ((rw >> 1) & 3)) << 3;
        gAs[s] = q2pk + (size_t)(m0 + rw) * DIM + scx;
    }
    // K staging: waves 0..2 stage rows w*32 .. w*32+31 (2 issues)
    const int krow0 = (w << 5) + arow, krow1 = krow0 + 16;
    const int sk0 = (aun ^ ((krow0 >> 1) & 3)) << 3;
    const int sk1 = (aun ^ ((krow1 >> 1) & 3)) << 3;
    const unsigned short* gK0 = k2 + kb + (size_t)krow0 * DIM + sk0;
    const unsigned short* gK1 = k2 + kb + (size_t)krow1 * DIM + sk1;
    const bool kw = (w < 3);
    const int lwA = w * 1536;   // wave-uniform A base (shorts): 48 rows * 32
    const int lwK = w << 10;    // wave-uniform K base (shorts): 32 rows * 32
    int offa[3], offk[6];
    #pragma unroll
    for (int i = 0; i < 3; i++) offa[i] = swz(w * 48 + i * 16 + r16, kq);
    #pragma unroll
    for (int j = 0; j < 6; j++) offk[j] = swz(j * 16 + r16, kq);
    f32x4 acc[3][6] = {};

    #pragma unroll
    for (int s = 0; s < 3; s++) gload16(gAs[s], AsBuf[0] + lwA + (s << 9));
    if (kw) {
        gload16(gK0, KsBuf[0] + lwK);
        gload16(gK1, KsBuf[0] + lwK + 512);
    }
    __syncthreads();

    #pragma unroll
    for (int t = 0; t < 16; t++) {
        const int cur = t & 1, nxt = cur ^ 1;
        if (t < 15) {
            const int ko = (t + 1) << 5;
            #pragma unroll
            for (int s = 0; s < 3; s++) gload16(gAs[s] + ko, AsBuf[nxt] + lwA + (s << 9));
            if (kw) {
                gload16(gK0 + ko, KsBuf[nxt] + lwK);
                gload16(gK1 + ko, KsBuf[nxt] + lwK + 512);
            }
        }
        bf16x8 af[3], bfr[6];
        #pragma unroll
        for (int i = 0; i < 3; i++)
            af[i] = *(const bf16x8*)(AsBuf[cur] + offa[i]);
        #pragma unroll
        for (int j = 0; j < 6; j++)
            bfr[j] = *(const bf16x8*)(KsBuf[cur] + offk[j]);
        __builtin_amdgcn_s_setprio(1);
        #pragma unroll
        for (int i = 0; i < 3; i++)
            #pragma unroll
            for (int j = 0; j < 6; j++)
                acc[i][j] = __builtin_amdgcn_mfma_f32_16x16x32_bf16(af[i], bfr[j], acc[i][j], 0, 0, 0);
        __builtin_amdgcn_s_setprio(0);
        if (t < 15) __syncthreads();
    }

    // in-register softmax over m (12 values per (row,t), split across lane pair lane^8)
    #pragma unroll
    for (int i = 0; i < 3; i++) {
        #pragma unroll
        for (int rr = 0; rr < 4; rr++) {
            float v0 = acc[i][0][rr], v1 = acc[i][1][rr], v2 = acc[i][2][rr];
            float v3 = acc[i][3][rr], v4 = acc[i][4][rr], v5 = acc[i][5][rr];
            float mx = fmaxf(fmaxf(fmaxf(v0, v1), fmaxf(v2, v3)), fmaxf(v4, v5));
            mx = fmaxf(mx, __shfl_xor(mx, 8, 64));
            float e0 = __expf(v0 - mx), e1 = __expf(v1 - mx), e2 = __expf(v2 - mx);
            float e3 = __expf(v3 - mx), e4 = __expf(v4 - mx), e5 = __expf(v5 - mx);
            float s = e0 + e1 + e2 + e3 + e4 + e5;
            s += __shfl_xor(s, 8, 64);
            float inv = 1.f / (96.f * s);
            acc[i][0][rr] = e0 * inv; acc[i][1][rr] = e1 * inv; acc[i][2][rr] = e2 * inv;
            acc[i][3][rr] = e3 * inv; acc[i][4][rr] = e4 * inv; acc[i][5][rr] = e5 * inv;
        }
    }

    // sum over l: in-lane over each 4-row group (whole group in one batch),
    // then scatter into per-wave LDS red[4 bl][96 col] (aliased onto dead AsBuf[0]).
    float* red = (float*)AsBuf[0];
    float* myred = red + w * 384;
    #pragma unroll
    for (int k = 0; k < 6; k++) myred[k * 64 + lane] = 0.f;
    __syncthreads();
    const int g = lane >> 4;
    #pragma unroll
    for (int i = 0; i < 3; i++) {
        int bl = (4 * i + g) / 3;
        #pragma unroll
        for (int j = 0; j < 6; j++) {
            float t = acc[i][j][0] + acc[i][j][1] + acc[i][j][2] + acc[i][j][3];
            atomicAdd(&myred[bl * 96 + j * 16 + r16], t);
        }
    }
    __syncthreads();
    const int bbase = bg * 16 + (w << 2);
    #pragma unroll
    for (int k = 0; k < 6; k++) {
        int idx = k * 64 + lane;
        int bl = idx / 96, col = idx - bl * 96;
        wout[((size_t)((bbase + bl) * NCLS + c)) * NTM + col] = myred[idx];
    }
}

// ---------- ctxraw[b,c,:] = sum_tm w[b,c,tm] * tfeb[c,tm,:]  (bf16 out) ----------
__global__ __launch_bounds__(256)
void ctx_kernel(const float* __restrict__ wbuf, const unsigned short* __restrict__ tfeb,
                unsigned short* __restrict__ ctxraw)
{
    __shared__ float ws[NTM * 16];
    const int bid = blockIdx.x;
    const int g = bid >> 5, r = bid & 31;
    const int c = g * 8 + (r & 7), bg = r >> 3;
    const int tid = threadIdx.x;
    for (int idx = tid; idx < 16 * NTM; idx += 256) {
        int bl = idx / NTM, tm = idx - bl * NTM;
        ws[tm * 16 + bl] = wbuf[((size_t)((bg * 16 + bl) * NCLS + c)) * NTM + tm];
    }
    __syncthreads();
    float a0[16] = {}, a1[16] = {};
    const unsigned int* vrow = (const unsigned int*)(tfeb + (size_t)c * NTM * DIM) + tid;
    #pragma unroll 4
    for (int tm = 0; tm < NTM; tm++) {
        unsigned int u = vrow[tm * 256];
        float vx = __uint_as_float(u << 16);
        float vy = __uint_as_float(u & 0xFFFF0000u);
        float wq[16];
        *(float4*)(wq + 0)  = *(const float4*)(ws + tm * 16 + 0);
        *(float4*)(wq + 4)  = *(const float4*)(ws + tm * 16 + 4);
        *(float4*)(wq + 8)  = *(const float4*)(ws + tm * 16 + 8);
        *(float4*)(wq + 12) = *(const float4*)(ws + tm * 16 + 12);
        #pragma unroll
        for (int bl = 0; bl < 16; bl++) {
            a0[bl] += wq[bl] * vx; a1[bl] += wq[bl] * vy;
        }
    }
    #pragma unroll
    for (int bl = 0; bl < 16; bl++) {
        int b = bg * 16 + bl;
        unsigned int o = (unsigned int)f2bf(a0[bl]) | ((unsigned int)f2bf(a1[bl]) << 16);
        ((unsigned int*)ctxraw)[(size_t)(b * NCLS + c) * 256 + tid] = o;
    }
}

// ---------- logits[b,c] = exp(ls) * sum_d imgn[b,d]/sqrt(n2[b,d]) * txt[b,c,d] ----------
__global__ __launch_bounds__(256)
void logits_kernel(const unsigned short* __restrict__ txt, const float* __restrict__ imgn,
                   const float* __restrict__ n2, const float* __restrict__ logit_scale,
                   float* __restrict__ out)
{
    __shared__ float lu[DIM];
    const int b = blockIdx.y, cg = blockIdx.x, tid = threadIdx.x;
    float els = expf(logit_scale[0]);
    lu[tid]       = els * imgn[b*DIM + tid]       * rsqrtf(n2[b*DIM + tid]);
    lu[tid + 256] = els * imgn[b*DIM + tid + 256] * rsqrtf(n2[b*DIM + tid + 256]);
    __syncthreads();
    int wave = tid >> 6, lane = tid & 63;
    int c = (cg << 2) + wave;
    const unsigned short* row = txt + (size_t)(b * NCLS + c) * DIM;
    ushort4 p0 = ((const ushort4*)row)[lane*2];
    ushort4 p1 = ((const ushort4*)row)[lane*2 + 1];
    int d0 = lane * 8;
    float s = bf2f(p0.x)*lu[d0]   + bf2f(p0.y)*lu[d0+1] + bf2f(p0.z)*lu[d0+2] + bf2f(p0.w)*lu[d0+3]
            + bf2f(p1.x)*lu[d0+4] + bf2f(p1.y)*lu[d0+5] + bf2f(p1.z)*lu[d0+6] + bf2f(p1.w)*lu[d0+7];
    #pragma unroll
    for (int off = 32; off > 0; off >>= 1) s += __shfl_down(s, off, 64);
    if (lane == 0) out[b*NCLS + c] = s;
}

extern "C" void kernel_launch(void* const* d_in, const int* in_sizes, int n_in,
                              void* d_out, int out_size, void* d_ws, size_t ws_size,
                              hipStream_t stream)
{
    const float* x   = (const float*)d_in[0];
    const float* tfe = (const float*)d_in[1];
    const float* siw = (const float*)d_in[2];
    const float* sib = (const float*)d_in[3];
    const float* sow = (const float*)d_in[4];
    const float* sob = (const float*)d_in[5];
    const float* ciw = (const float*)d_in[6];
    const float* cib = (const float*)d_in[7];
    const float* cow = (const float*)d_in[8];
    const float* cob = (const float*)d_in[9];
    const float* ls  = (const float*)d_in[10];
    float* out = (float*)d_out;

    char* p = (char*)d_ws;
    auto alloc = [&](size_t bytes) { char* r = p; p += (bytes + 255) & ~255ull; return r; };
    unsigned short* tfeb   = (unsigned short*)alloc((size_t)49152000 * 2);   // 98.3 MB
    unsigned short* ctxraw = (unsigned short*)alloc((size_t)BATCH * NCLS * DIM * 2);  // 65.5 MB
    float* wbuf            = (float*)alloc((size_t)BATCH * NCLS * NTM * 4);  // 24.6 MB
    float* qkv             = (float*)alloc((size_t)768 * 1536 * 4);
    float* ao              = (float*)alloc((size_t)768 * DIM * 4);
    float* xs              = (float*)alloc((size_t)768 * DIM * 4);
    float* q2s             = (float*)alloc((size_t)768 * DIM * 4);
    float* q2k             = (float*)alloc((size_t)768 * DIM * 4);
    unsigned short* q2pk   = (unsigned short*)alloc((size_t)768 * DIM * 2);
    unsigned short* Wvob   = (unsigned short*)alloc((size_t)DIM * DIM * 2);
    float* bvo             = (float*)alloc(DIM * 4);
    float* n2              = (float*)alloc(BATCH * DIM * 4);
    float* imgn            = (float*)alloc(BATCH * DIM * 4);
    unsigned short* txt    = tfeb;   // alias: tfeb dead after ctx_kernel; txt written after

    hipMemsetAsync(n2, 0, BATCH * DIM * 4, stream);

    // weight/text prep
    f2bf_kernel<<<48000, 256, 0, stream>>>(tfe, tfeb, 49152000);
    fold_wvo<<<512, 256, 0, stream>>>(cow, ciw + 1024*512, cib + 1024, cob, Wvob, bvo);

    // self-attn head (fp32, small)
    gemm_bt_f32<<<dim3(24, 12), 256, 0, stream>>>(x, siw, sib, qkv, 768, 1536, 512, 1.f);
    attn_kernel<<<64, 256, 0, stream>>>(qkv, ao);
    gemm_bt_f32<<<dim3(8, 12), 256, 0, stream>>>(ao, sow, sob, xs, 768, 512, 512, 1.f);
    img_kernel<<<64, 256, 0, stream>>>(xs, imgn);
    gemm_bt_f32<<<dim3(8, 12), 256, 0, stream>>>(xs, ciw, cib, q2s, 768, 512, 512, SCALEF);
    // fold cWk into query: q2k = q2s @ cWk   (k-bias cancels in softmax over m)
    gemm_nt_f32<<<dim3(8, 12), 256, 0, stream>>>(q2s, ciw + 512*512, q2k, 768, 512, 512);
    build_q2p<<<dim3(12, 64), 256, 0, stream>>>(q2k, q2pk);

    // fused scores+softmax -> w[b,c,96]  (K = raw text features; XCD-grouped 1-D grid)
    fused_scores<<<4000, 256, 0, stream>>>(q2pk, tfeb, wbuf);

    // ctxraw = w @ tf  (value projection deferred past the template/layer average)
    ctx_kernel<<<4000, 256, 0, stream>>>(wbuf, tfeb, ctxraw);

    // txt = ctxraw @ Wvob^T + (bvo + cob)   (MFMA, 64000 rows; n2 fused in epilogue)
    gemm_mfma<unsigned short><<<dim3(4, 500), 256, 0, stream>>>(
        ctxraw, Wvob, bvo, txt, 64000, 512, 1.f, n2);

    // logits
    logits_kernel<<<dim3(250, 64), 256, 0, stream>>>(txt, imgn, n2, ls, out);
}

// Round 10
// 749.788 us; speedup vs baseline: 1.0812x; 1.0812x over previous
//
#include <hip/hip_runtime.h>

#define L_IMG 12
#define BATCH 64
#define NCLS  1000
#define DIM   512
#define NTM   96
#define SCALEF 0.044194173824159216f   // 1/sqrt(512)

typedef __attribute__((ext_vector_type(8))) short bf16x8;
typedef __attribute__((ext_vector_type(4))) float f32x4;

// ---------- bf16 helpers ----------
__device__ __forceinline__ float bf2f(unsigned short u) {
    return __uint_as_float(((unsigned int)u) << 16);
}
__device__ __forceinline__ unsigned short f2bf(float f) {
    unsigned int u = __float_as_uint(f);
    u += 0x7FFFu + ((u >> 16) & 1u);
    return (unsigned short)(u >> 16);
}
__device__ __forceinline__ void storeo(float* p, float v) { *p = v; }
__device__ __forceinline__ void storeo(unsigned short* p, float v) { *p = f2bf(v); }

// XOR-swizzled LDS offset (shorts) for [row][32-short] tiles: 16B unit u ^= (row>>1)&3.
__device__ __forceinline__ int swz(int row, int u) {
    return (row << 5) + ((u ^ ((row >> 1) & 3)) << 3);
}

// async global->LDS, 16 B per lane; LDS dest = wave-uniform base + lane*16 (linear).
// Swizzle achieved by inverse-permuting the per-lane GLOBAL source (rule #21).
__device__ __forceinline__ void gload16(const unsigned short* g, unsigned short* l) {
    __builtin_amdgcn_global_load_lds(
        (const __attribute__((address_space(1))) void*)g,
        (__attribute__((address_space(3))) void*)l, 16, 0, 0);
}

// ---------- fp32 -> bf16 convert (n multiple of 4) ----------
__global__ __launch_bounds__(256)
void f2bf_kernel(const float* __restrict__ in, unsigned short* __restrict__ out, int n)
{
    int i = (blockIdx.x * 256 + threadIdx.x) * 4;
    if (i < n) {
        float4 v = *(const float4*)(in + i);
        ushort4 o;
        o.x = f2bf(v.x); o.y = f2bf(v.y); o.z = f2bf(v.z); o.w = f2bf(v.w);
        *(ushort4*)(out + i) = o;
    }
}

// ---------- Wvo[d,k] = sum_e cow[d,e]*cWv[e,k] (bf16), bvo[d] = cow[d,:].cbv + cob[d] ----------
__global__ __launch_bounds__(256)
void fold_wvo(const float* __restrict__ cow, const float* __restrict__ cWv,
              const float* __restrict__ cbv, const float* __restrict__ cob,
              unsigned short* __restrict__ Wvob, float* __restrict__ bvo)
{
    __shared__ float crow[DIM];
    __shared__ float red[256];
    const int d = blockIdx.x, t = threadIdx.x;
    float c0 = cow[d * DIM + t], c1 = cow[d * DIM + t + 256];
    crow[t] = c0; crow[t + 256] = c1;
    red[t] = c0 * cbv[t] + c1 * cbv[t + 256];
    __syncthreads();
    for (int s = 128; s > 0; s >>= 1) {
        if (t < s) red[t] += red[t + s];
        __syncthreads();
    }
    if (t == 0) bvo[d] = red[0] + cob[d];
    float a0 = 0.f, a1 = 0.f;
    for (int e = 0; e < DIM; e++) {
        float ce = crow[e];
        a0 += ce * cWv[e * DIM + t];
        a1 += ce * cWv[e * DIM + t + 256];
    }
    Wvob[d * DIM + t]       = f2bf(a0);
    Wvob[d * DIM + t + 256] = f2bf(a1);
}

// ---------- small fp32 tiled GEMM: C[M,N] = (A[M,K] @ W[N,K]^T + bias) * scale ----------
#define BKT 32
#define LDT 68
__global__ __launch_bounds__(256)
void gemm_bt_f32(const float* __restrict__ A, const float* __restrict__ W,
                 const float* __restrict__ bias, float* __restrict__ Co,
                 int M, int N, int K, float out_scale)
{
    __shared__ float As[BKT * LDT];
    __shared__ float Ws[BKT * LDT];
    const int tid = threadIdx.x;
    const int m0 = blockIdx.y << 6, n0 = blockIdx.x << 6;
    const int tx = tid & 15, ty = tid >> 4;
    float acc[4][4] = {};
    for (int k0 = 0; k0 < K; k0 += BKT) {
        #pragma unroll
        for (int i = 0; i < 2; i++) {
            int slot = tid + (i << 8);
            int r = slot >> 3, kq = slot & 7;
            float4 v = *(const float4*)(A + (size_t)(m0 + r) * K + k0 + (kq << 2));
            As[(kq*4+0)*LDT + r] = v.x; As[(kq*4+1)*LDT + r] = v.y;
            As[(kq*4+2)*LDT + r] = v.z; As[(kq*4+3)*LDT + r] = v.w;
            float4 w = *(const float4*)(W + (size_t)(n0 + r) * K + k0 + (kq << 2));
            Ws[(kq*4+0)*LDT + r] = w.x; Ws[(kq*4+1)*LDT + r] = w.y;
            Ws[(kq*4+2)*LDT + r] = w.z; Ws[(kq*4+3)*LDT + r] = w.w;
        }
        __syncthreads();
        #pragma unroll
        for (int kk = 0; kk < BKT; kk++) {
            float4 a = *(const float4*)(As + kk*LDT + ty*4);
            float4 w = *(const float4*)(Ws + kk*LDT + tx*4);
            acc[0][0] += a.x*w.x; acc[0][1] += a.x*w.y; acc[0][2] += a.x*w.z; acc[0][3] += a.x*w.w;
            acc[1][0] += a.y*w.x; acc[1][1] += a.y*w.y; acc[1][2] += a.y*w.z; acc[1][3] += a.y*w.w;
            acc[2][0] += a.z*w.x; acc[2][1] += a.z*w.y; acc[2][2] += a.z*w.z; acc[2][3] += a.z*w.w;
            acc[3][0] += a.w*w.x; acc[3][1] += a.w*w.y; acc[3][2] += a.w*w.z; acc[3][3] += a.w*w.w;
        }
        __syncthreads();
    }
    #pragma unroll
    for (int i = 0; i < 4; i++) {
        int mr = m0 + ty*4 + i;
        #pragma unroll
        for (int j = 0; j < 4; j++) {
            int n = n0 + tx*4 + j;
            float v = acc[i][j];
            if (bias) v += bias[n];
            Co[(size_t)mr * N + n] = v * out_scale;
        }
    }
}

// ---------- small fp32 GEMM, B NOT transposed: C[M,N] = A[M,K] @ W[K,N] ----------
__global__ __launch_bounds__(256)
void gemm_nt_f32(const float* __restrict__ A, const float* __restrict__ W,
                 float* __restrict__ Co, int M, int N, int K)
{
    __shared__ float As[BKT * LDT];
    __shared__ float Ws[BKT * LDT];
    const int tid = threadIdx.x;
    const int m0 = blockIdx.y << 6, n0 = blockIdx.x << 6;
    const int tx = tid & 15, ty = tid >> 4;
    float acc[4][4] = {};
    for (int k0 = 0; k0 < K; k0 += BKT) {
        #pragma unroll
        for (int i = 0; i < 2; i++) {
            int slot = tid + (i << 8);
            int r = slot >> 3, kq = slot & 7;
            float4 v = *(const float4*)(A + (size_t)(m0 + r) * K + k0 + (kq << 2));
            As[(kq*4+0)*LDT + r] = v.x; As[(kq*4+1)*LDT + r] = v.y;
            As[(kq*4+2)*LDT + r] = v.z; As[(kq*4+3)*LDT + r] = v.w;
            int kr = slot >> 4, c4 = slot & 15;
            *(float4*)(Ws + kr*LDT + c4*4) =
                *(const float4*)(W + (size_t)(k0 + kr) * N + n0 + (c4 << 2));
        }
        __syncthreads();
        #pragma unroll
        for (int kk = 0; kk < BKT; kk++) {
            float4 a = *(const float4*)(As + kk*LDT + ty*4);
            float4 w = *(const float4*)(Ws + kk*LDT + tx*4);
            acc[0][0] += a.x*w.x; acc[0][1] += a.x*w.y; acc[0][2] += a.x*w.z; acc[0][3] += a.x*w.w;
            acc[1][0] += a.y*w.x; acc[1][1] += a.y*w.y; acc[1][2] += a.y*w.z; acc[1][3] += a.y*w.w;
            acc[2][0] += a.z*w.x; acc[2][1] += a.z*w.y; acc[2][2] += a.z*w.z; acc[2][3] += a.z*w.w;
            acc[3][0] += a.w*w.x; acc[3][1] += a.w*w.y; acc[3][2] += a.w*w.z; acc[3][3] += a.w*w.w;
        }
        __syncthreads();
    }
    #pragma unroll
    for (int i = 0; i < 4; i++) {
        int mr = m0 + ty*4 + i;
        #pragma unroll
        for (int j = 0; j < 4; j++)
            Co[(size_t)mr * N + n0 + tx*4 + j] = acc[i][j];
    }
}

// ---------- self-attention over the 12-layer axis, one block per batch ----------
__global__ __launch_bounds__(256)
void attn_kernel(const float* __restrict__ qkv, float* __restrict__ ao)
{
    __shared__ float lq[L_IMG * DIM];
    __shared__ float lk[L_IMG * DIM];
    __shared__ float sc[L_IMG * L_IMG];
    __shared__ float sa[L_IMG * L_IMG];
    const int b = blockIdx.x, tid = threadIdx.x;
    for (int i = 0; i < 6; i++) {
        int slot = tid + (i << 8);
        int l = slot >> 7, e4 = slot & 127;
        const float* row = qkv + (size_t)(l * BATCH + b) * 1536;
        *(float4*)(lq + l*DIM + e4*4) = *(const float4*)(row + e4*4);
        *(float4*)(lk + l*DIM + e4*4) = *(const float4*)(row + DIM + e4*4);
    }
    __syncthreads();
    if (tid < 144) {
        int l = tid / 12, m = tid % 12;
        float a = 0.f;
        for (int d4 = 0; d4 < 128; d4++) {
            float4 q = *(const float4*)(lq + l*DIM + d4*4);
            float4 k = *(const float4*)(lk + m*DIM + d4*4);
            a += q.x*k.x + q.y*k.y + q.z*k.z + q.w*k.w;
        }
        sc[tid] = a * SCALEF;
    }
    __syncthreads();
    if (tid < 12) {
        float mx = -1e30f;
        for (int m = 0; m < 12; m++) mx = fmaxf(mx, sc[tid*12 + m]);
        float e[12], s = 0.f;
        for (int m = 0; m < 12; m++) { e[m] = __expf(sc[tid*12 + m] - mx); s += e[m]; }
        float inv = 1.f / s;
        for (int m = 0; m < 12; m++) sa[tid*12 + m] = e[m] * inv;
    }
    __syncthreads();
    for (int i = 0; i < 2; i++) {
        int e = tid + (i << 8);
        float vv[12];
        #pragma unroll
        for (int m = 0; m < 12; m++)
            vv[m] = qkv[(size_t)(m * BATCH + b) * 1536 + 1024 + e];
        #pragma unroll
        for (int l = 0; l < 12; l++) {
            float a = 0.f;
            #pragma unroll
            for (int m = 0; m < 12; m++) a += sa[l*12 + m] * vv[m];
            ao[(size_t)(l * BATCH + b) * DIM + e] = a;
        }
    }
}

// ---------- normalize image features (xs layer 11) ----------
__global__ __launch_bounds__(256)
void img_kernel(const float* __restrict__ xs, float* __restrict__ imgn)
{
    __shared__ float red[256];
    const int b = blockIdx.x, tid = threadIdx.x;
    const float* row = xs + (size_t)(11 * BATCH + b) * DIM;
    float v0 = row[tid], v1 = row[tid + 256];
    red[tid] = v0*v0 + v1*v1;
    __syncthreads();
    for (int s = 128; s > 0; s >>= 1) {
        if (tid < s) red[tid] += red[tid + s];
        __syncthreads();
    }
    float inv = rsqrtf(red[0]);
    imgn[b*DIM + tid]       = v0 * inv;
    imgn[b*DIM + tid + 256] = v1 * inv;
}

// ---------- q2k fp32 [12,64,512] -> q2pb bf16 [64*16, 512], l>=12 zero ----------
__global__ __launch_bounds__(256)
void build_q2p(const float* __restrict__ q2s, unsigned short* __restrict__ q2pb)
{
    const int l = blockIdx.x, b = blockIdx.y, t = threadIdx.x;
    int d0 = t * 2;
    unsigned int o = 0;
    if (l < 12) {
        float2 v = *(const float2*)(q2s + (size_t)(l * BATCH + b) * DIM + d0);
        o = (unsigned int)f2bf(v.x) | ((unsigned int)f2bf(v.y) << 16);
    }
    ((unsigned int*)q2pb)[(size_t)(b * 16 + l) * 256 + t] = o;
}

// ---------- MFMA GEMM: C[M,N] = A[M,K]@W[N,K]^T + bias ; 128x128 tile, BK=32 ----------
// Async global_load_lds staging, double-buffered. Optional fused n2: per-column
// sum of v^2 (fp32, pre-rounding), shfl-reduced across row-groups, global atomics.
// Row index m = b*NCLS + c; a 128-row tile straddles at most one b-boundary.
template<typename OutT>
__global__ __launch_bounds__(256, 4)
void gemm_mfma(const unsigned short* __restrict__ A, const unsigned short* __restrict__ W,
               const float* __restrict__ bias, OutT* __restrict__ Co,
               int M, int N, float scale, float* __restrict__ n2)
{
    const int K = DIM;
    __shared__ __align__(16) unsigned short AsBuf[2][128 * 32];
    __shared__ __align__(16) unsigned short WsBuf[2][128 * 32];
    const int m0 = blockIdx.y << 7, n0 = blockIdx.x << 7;
    const int tid = threadIdx.x;
    const int w = tid >> 6, lane = tid & 63;
    const int mt0 = (w & 1) * 4, nt0 = (w >> 1) * 4;
    const int r16 = lane & 15, kq = lane >> 4;
    const int row0 = (w << 5) + (lane >> 2), row1 = row0 + 16;
    const int sc0 = ((lane & 3) ^ ((row0 >> 1) & 3)) << 3;
    const int sc1 = ((lane & 3) ^ ((row1 >> 1) & 3)) << 3;
    const unsigned short* gA0 = A + (size_t)(m0 + row0) * K + sc0;
    const unsigned short* gA1 = A + (size_t)(m0 + row1) * K + sc1;
    const unsigned short* gW0 = W + (size_t)(n0 + row0) * K + sc0;
    const unsigned short* gW1 = W + (size_t)(n0 + row1) * K + sc1;
    const int lw = w << 10;
    int offa[4], offb[4];
    #pragma unroll
    for (int i = 0; i < 4; i++) {
        offa[i] = swz((mt0 + i) * 16 + r16, kq);
        offb[i] = swz((nt0 + i) * 16 + r16, kq);
    }
    f32x4 acc[4][4] = {};

    gload16(gA0, AsBuf[0] + lw);
    gload16(gA1, AsBuf[0] + lw + 512);
    gload16(gW0, WsBuf[0] + lw);
    gload16(gW1, WsBuf[0] + lw + 512);
    __syncthreads();

    #pragma unroll
    for (int t = 0; t < 16; t++) {
        const int cur = t & 1, nxt = cur ^ 1;
        if (t < 15) {
            const int ko = (t + 1) << 5;
            gload16(gA0 + ko, AsBuf[nxt] + lw);
            gload16(gA1 + ko, AsBuf[nxt] + lw + 512);
            gload16(gW0 + ko, WsBuf[nxt] + lw);
            gload16(gW1 + ko, WsBuf[nxt] + lw + 512);
        }
        bf16x8 af[4], bfr[4];
        #pragma unroll
        for (int i = 0; i < 4; i++) {
            af[i]  = *(const bf16x8*)(AsBuf[cur] + offa[i]);
            bfr[i] = *(const bf16x8*)(WsBuf[cur] + offb[i]);
        }
        #pragma unroll
        for (int i = 0; i < 4; i++)
            #pragma unroll
            for (int j = 0; j < 4; j++)
                acc[i][j] = __builtin_amdgcn_mfma_f32_16x16x32_bf16(af[i], bfr[j], acc[i][j], 0, 0, 0);
        if (t < 15) __syncthreads();
    }
    const int rbase = (lane >> 4) * 4;
    const int b0 = m0 / NCLS;
    const int splitrow = (b0 + 1) * NCLS;
    #pragma unroll
    for (int j = 0; j < 4; j++) {
        int gcol = n0 + (nt0 + j) * 16 + r16;
        float bv = bias ? bias[gcol] : 0.f;
        float s0 = 0.f, s1 = 0.f;
        #pragma unroll
        for (int i = 0; i < 4; i++)
            #pragma unroll
            for (int r = 0; r < 4; r++) {
                int grow = m0 + (mt0 + i) * 16 + rbase + r;
                float v = acc[i][j][r] * scale + bv;
                storeo(Co + (size_t)grow * N + gcol, v);
                if (n2) { if (grow < splitrow) s0 += v * v; else s1 += v * v; }
            }
        if (n2) {
            s0 += __shfl_xor(s0, 16, 64); s0 += __shfl_xor(s0, 32, 64);
            s1 += __shfl_xor(s1, 16, 64); s1 += __shfl_xor(s1, 32, 64);
            if (lane < 16) {
                atomicAdd(&n2[(size_t)b0 * N + gcol], s0);
                if (splitrow < m0 + 128) atomicAdd(&n2[(size_t)(b0 + 1) * N + gcol], s1);
            }
        }
    }
}

// ---------- fused scores + softmax(m) + sum_l: one block = (class c, 16 batches) ----------
// R8 known-good version: 256 rows/block (16 b * 16, l>=12 zero-padded), wave = 64 rows
// x 96 cols (acc[4][6]). K-source is tfeb directly (cWk folded into query; k-bias
// cancels in softmax). Async global_load_lds staging; XCD-grouped 1-D grid.
__global__ __launch_bounds__(256, 3)
void fused_scores(const unsigned short* __restrict__ q2pb, const unsigned short* __restrict__ k2,
                  float* __restrict__ wout)
{
    __shared__ __align__(16) unsigned short AsBuf[2][256 * 32];  // 2 x 16384 B
    __shared__ __align__(16) unsigned short KsBuf[2][96 * 32];   // 2 x  6144 B
    const int bid = blockIdx.x;
    const int g8 = bid >> 5, r = bid & 31;
    const int c = g8 * 8 + (r & 7), bg = r >> 3;     // bg in 0..3, 16 batches each
    const int tid = threadIdx.x;
    const int m0 = bg << 8;
    const int w = tid >> 6, lane = tid & 63;
    const int r16 = lane & 15, kq = lane >> 4;
    const size_t kb = (size_t)c * NTM * DIM;
    const int arow = lane >> 2, aun = lane & 3;
    // A staging: wave w stages rows w*64 .. w*64+63 (4 issues x 16 rows)
    const unsigned short* gAs[4];
    #pragma unroll
    for (int s = 0; s < 4; s++) {
        int rw = (w << 6) + (s << 4) + arow;
        int scx = (aun ^ ((rw >> 1) & 3)) << 3;
        gAs[s] = q2pb + (size_t)(m0 + rw) * DIM + scx;
    }
    // K staging: waves 0..2 stage rows w*32 .. w*32+31 (2 issues)
    const int krow0 = (w << 5) + arow, krow1 = krow0 + 16;
    const int sk0 = (aun ^ ((krow0 >> 1) & 3)) << 3;
    const int sk1 = (aun ^ ((krow1 >> 1) & 3)) << 3;
    const unsigned short* gK0 = k2 + kb + (size_t)krow0 * DIM + sk0;
    const unsigned short* gK1 = k2 + kb + (size_t)krow1 * DIM + sk1;
    const bool kw = (w < 3);
    const int lwA = w << 11;   // wave-uniform A base (shorts): 64 rows * 32
    const int lwK = w << 10;   // wave-uniform K base (shorts): 32 rows * 32
    int offa[4], offk[6];
    #pragma unroll
    for (int i = 0; i < 4; i++) offa[i] = swz((w << 6) + i * 16 + r16, kq);
    #pragma unroll
    for (int j = 0; j < 6; j++) offk[j] = swz(j * 16 + r16, kq);
    f32x4 acc[4][6] = {};

    #pragma unroll
    for (int s = 0; s < 4; s++) gload16(gAs[s], AsBuf[0] + lwA + (s << 9));
    if (kw) {
        gload16(gK0, KsBuf[0] + lwK);
        gload16(gK1, KsBuf[0] + lwK + 512);
    }
    __syncthreads();

    #pragma unroll
    for (int t = 0; t < 16; t++) {
        const int cur = t & 1, nxt = cur ^ 1;
        if (t < 15) {
            const int ko = (t + 1) << 5;
            #pragma unroll
            for (int s = 0; s < 4; s++) gload16(gAs[s] + ko, AsBuf[nxt] + lwA + (s << 9));
            if (kw) {
                gload16(gK0 + ko, KsBuf[nxt] + lwK);
                gload16(gK1 + ko, KsBuf[nxt] + lwK + 512);
            }
        }
        bf16x8 af[4], bfr[6];
        #pragma unroll
        for (int i = 0; i < 4; i++)
            af[i] = *(const bf16x8*)(AsBuf[cur] + offa[i]);
        #pragma unroll
        for (int j = 0; j < 6; j++)
            bfr[j] = *(const bf16x8*)(KsBuf[cur] + offk[j]);
        __builtin_amdgcn_s_setprio(1);
        #pragma unroll
        for (int i = 0; i < 4; i++)
            #pragma unroll
            for (int j = 0; j < 6; j++)
                acc[i][j] = __builtin_amdgcn_mfma_f32_16x16x32_bf16(af[i], bfr[j], acc[i][j], 0, 0, 0);
        __builtin_amdgcn_s_setprio(0);
        if (t < 15) __syncthreads();
    }

    // in-register softmax over m (12 values per (row,t), split across lane pair lane^8)
    #pragma unroll
    for (int i = 0; i < 4; i++) {
        #pragma unroll
        for (int rr = 0; rr < 4; rr++) {
            float v0 = acc[i][0][rr], v1 = acc[i][1][rr], v2 = acc[i][2][rr];
            float v3 = acc[i][3][rr], v4 = acc[i][4][rr], v5 = acc[i][5][rr];
            float mx = fmaxf(fmaxf(fmaxf(v0, v1), fmaxf(v2, v3)), fmaxf(v4, v5));
            mx = fmaxf(mx, __shfl_xor(mx, 8, 64));
            float e0 = __expf(v0 - mx), e1 = __expf(v1 - mx), e2 = __expf(v2 - mx);
            float e3 = __expf(v3 - mx), e4 = __expf(v4 - mx), e5 = __expf(v5 - mx);
            float s = e0 + e1 + e2 + e3 + e4 + e5;
            s += __shfl_xor(s, 8, 64);
            float inv = 1.f / (96.f * s);
            acc[i][0][rr] = e0 * inv; acc[i][1][rr] = e1 * inv; acc[i][2][rr] = e2 * inv;
            acc[i][3][rr] = e3 * inv; acc[i][4][rr] = e4 * inv; acc[i][5][rr] = e5 * inv;
        }
    }

    // sum over l: in-lane over 4 rows (groups 0..2 = l 0..11; group 3 = pad),
    // then across row-groups via shfl_xor(16/32).
    const bool contrib = (lane >> 4) < 3;
    #pragma unroll
    for (int i = 0; i < 4; i++) {
        float s6[6];
        #pragma unroll
        for (int j = 0; j < 6; j++) {
            float t = contrib ? (acc[i][j][0] + acc[i][j][1] + acc[i][j][2] + acc[i][j][3]) : 0.f;
            t += __shfl_xor(t, 16, 64);
            t += __shfl_xor(t, 32, 64);
            s6[j] = t;
        }
        if (lane < 16) {
            const int b = bg * 16 + (w << 2) + i;
            float* dst = wout + ((size_t)(b * NCLS + c)) * NTM;
            #pragma unroll
            for (int j = 0; j < 6; j++)
                dst[j * 16 + r16] = s6[j];
        }
    }
}

// ---------- ctxraw[b,c,:] = sum_tm w[b,c,tm] * tfeb[c,tm,:]  (bf16 out) ----------
__global__ __launch_bounds__(256)
void ctx_kernel(const float* __restrict__ wbuf, const unsigned short* __restrict__ tfeb,
                unsigned short* __restrict__ ctxraw)
{
    __shared__ float ws[NTM * 16];
    const int bid = blockIdx.x;
    const int g = bid >> 5, r = bid & 31;
    const int c = g * 8 + (r & 7), bg = r >> 3;
    const int tid = threadIdx.x;
    for (int idx = tid; idx < 16 * NTM; idx += 256) {
        int bl = idx / NTM, tm = idx - bl * NTM;
        ws[tm * 16 + bl] = wbuf[((size_t)((bg * 16 + bl) * NCLS + c)) * NTM + tm];
    }
    __syncthreads();
    float a0[16] = {}, a1[16] = {};
    const unsigned int* vrow = (const unsigned int*)(tfeb + (size_t)c * NTM * DIM) + tid;
    #pragma unroll 4
    for (int tm = 0; tm < NTM; tm++) {
        unsigned int u = vrow[tm * 256];
        float vx = __uint_as_float(u << 16);
        float vy = __uint_as_float(u & 0xFFFF0000u);
        float wq[16];
        *(float4*)(wq + 0)  = *(const float4*)(ws + tm * 16 + 0);
        *(float4*)(wq + 4)  = *(const float4*)(ws + tm * 16 + 4);
        *(float4*)(wq + 8)  = *(const float4*)(ws + tm * 16 + 8);
        *(float4*)(wq + 12) = *(const float4*)(ws + tm * 16 + 12);
        #pragma unroll
        for (int bl = 0; bl < 16; bl++) {
            a0[bl] += wq[bl] * vx; a1[bl] += wq[bl] * vy;
        }
    }
    #pragma unroll
    for (int bl = 0; bl < 16; bl++) {
        int b = bg * 16 + bl;
        unsigned int o = (unsigned int)f2bf(a0[bl]) | ((unsigned int)f2bf(a1[bl]) << 16);
        ((unsigned int*)ctxraw)[(size_t)(b * NCLS + c) * 256 + tid] = o;
    }
}

// ---------- logits[b,c] = exp(ls) * sum_d imgn[b,d]/sqrt(n2[b,d]) * txt[b,c,d] ----------
__global__ __launch_bounds__(256)
void logits_kernel(const unsigned short* __restrict__ txt, const float* __restrict__ imgn,
                   const float* __restrict__ n2, const float* __restrict__ logit_scale,
                   float* __restrict__ out)
{
    __shared__ float lu[DIM];
    const int b = blockIdx.y, cg = blockIdx.x, tid = threadIdx.x;
    float els = expf(logit_scale[0]);
    lu[tid]       = els * imgn[b*DIM + tid]       * rsqrtf(n2[b*DIM + tid]);
    lu[tid + 256] = els * imgn[b*DIM + tid + 256] * rsqrtf(n2[b*DIM + tid + 256]);
    __syncthreads();
    int wave = tid >> 6, lane = tid & 63;
    int c = (cg << 2) + wave;
    const unsigned short* row = txt + (size_t)(b * NCLS + c) * DIM;
    ushort4 p0 = ((const ushort4*)row)[lane*2];
    ushort4 p1 = ((const ushort4*)row)[lane*2 + 1];
    int d0 = lane * 8;
    float s = bf2f(p0.x)*lu[d0]   + bf2f(p0.y)*lu[d0+1] + bf2f(p0.z)*lu[d0+2] + bf2f(p0.w)*lu[d0+3]
            + bf2f(p1.x)*lu[d0+4] + bf2f(p1.y)*lu[d0+5] + bf2f(p1.z)*lu[d0+6] + bf2f(p1.w)*lu[d0+7];
    #pragma unroll
    for (int off = 32; off > 0; off >>= 1) s += __shfl_down(s, off, 64);
    if (lane == 0) out[b*NCLS + c] = s;
}

extern "C" void kernel_launch(void* const* d_in, const int* in_sizes, int n_in,
                              void* d_out, int out_size, void* d_ws, size_t ws_size,
                              hipStream_t stream)
{
    const float* x   = (const float*)d_in[0];
    const float* tfe = (const float*)d_in[1];
    const float* siw = (const float*)d_in[2];
    const float* sib = (const float*)d_in[3];
    const float* sow = (const float*)d_in[4];
    const float* sob = (const float*)d_in[5];
    const float* ciw = (const float*)d_in[6];
    const float* cib = (const float*)d_in[7];
    const float* cow = (const float*)d_in[8];
    const float* cob = (const float*)d_in[9];
    const float* ls  = (const float*)d_in[10];
    float* out = (float*)d_out;

    char* p = (char*)d_ws;
    auto alloc = [&](size_t bytes) { char* r = p; p += (bytes + 255) & ~255ull; return r; };
    unsigned short* tfeb   = (unsigned short*)alloc((size_t)49152000 * 2);   // 98.3 MB
    unsigned short* ctxraw = (unsigned short*)alloc((size_t)BATCH * NCLS * DIM * 2);  // 65.5 MB
    float* wbuf            = (float*)alloc((size_t)BATCH * NCLS * NTM * 4);  // 24.6 MB
    float* qkv             = (float*)alloc((size_t)768 * 1536 * 4);
    float* ao              = (float*)alloc((size_t)768 * DIM * 4);
    float* xs              = (float*)alloc((size_t)768 * DIM * 4);
    float* q2s             = (float*)alloc((size_t)768 * DIM * 4);
    float* q2k             = (float*)alloc((size_t)768 * DIM * 4);
    unsigned short* q2pb   = (unsigned short*)alloc((size_t)1024 * DIM * 2);
    unsigned short* Wvob   = (unsigned short*)alloc((size_t)DIM * DIM * 2);
    float* bvo             = (float*)alloc(DIM * 4);
    float* n2              = (float*)alloc(BATCH * DIM * 4);
    float* imgn            = (float*)alloc(BATCH * DIM * 4);
    unsigned short* txt    = tfeb;   // alias: tfeb dead after ctx_kernel; txt written after

    hipMemsetAsync(n2, 0, BATCH * DIM * 4, stream);

    // weight/text prep
    f2bf_kernel<<<48000, 256, 0, stream>>>(tfe, tfeb, 49152000);
    fold_wvo<<<512, 256, 0, stream>>>(cow, ciw + 1024*512, cib + 1024, cob, Wvob, bvo);

    // self-attn head (fp32, small)
    gemm_bt_f32<<<dim3(24, 12), 256, 0, stream>>>(x, siw, sib, qkv, 768, 1536, 512, 1.f);
    attn_kernel<<<64, 256, 0, stream>>>(qkv, ao);
    gemm_bt_f32<<<dim3(8, 12), 256, 0, stream>>>(ao, sow, sob, xs, 768, 512, 512, 1.f);
    img_kernel<<<64, 256, 0, stream>>>(xs, imgn);
    gemm_bt_f32<<<dim3(8, 12), 256, 0, stream>>>(xs, ciw, cib, q2s, 768, 512, 512, SCALEF);
    // fold cWk into query: q2k = q2s @ cWk   (k-bias cancels in softmax over m)
    gemm_nt_f32<<<dim3(8, 12), 256, 0, stream>>>(q2s, ciw + 512*512, q2k, 768, 512, 512);
    build_q2p<<<dim3(16, 64), 256, 0, stream>>>(q2k, q2pb);

    // fused scores+softmax -> w[b,c,96]  (K = raw text features; XCD-grouped 1-D grid)
    fused_scores<<<4000, 256, 0, stream>>>(q2pb, tfeb, wbuf);

    // ctxraw = w @ tf  (value projection deferred past the template/layer average)
    ctx_kernel<<<4000, 256, 0, stream>>>(wbuf, tfeb, ctxraw);

    // txt = ctxraw @ Wvob^T + (bvo + cob)   (MFMA, 64000 rows; n2 fused in epilogue)
    gemm_mfma<unsigned short><<<dim3(4, 500), 256, 0, stream>>>(
        ctxraw, Wvob, bvo, txt, 64000, 512, 1.f, n2);

    // logits
    logits_kernel<<<dim3(250, 64), 256, 0, stream>>>(txt, imgn, n2, ls, out);
}

// Round 11
// 706.663 us; speedup vs baseline: 1.1472x; 1.0610x over previous
//
#include <hip/hip_runtime.h>

#define L_IMG 12
#define BATCH 64
#define NCLS  1000
#define DIM   512
#define NTM   96
#define SCALEF 0.044194173824159216f   // 1/sqrt(512)

typedef __attribute__((ext_vector_type(8))) short bf16x8;
typedef __attribute__((ext_vector_type(4))) float f32x4;

// ---------- bf16 helpers ----------
__device__ __forceinline__ float bf2f(unsigned short u) {
    return __uint_as_float(((unsigned int)u) << 16);
}
__device__ __forceinline__ unsigned short f2bf(float f) {
    unsigned int u = __float_as_uint(f);
    u += 0x7FFFu + ((u >> 16) & 1u);
    return (unsigned short)(u >> 16);
}
__device__ __forceinline__ void storeo(float* p, float v) { *p = v; }
__device__ __forceinline__ void storeo(unsigned short* p, float v) { *p = f2bf(v); }

// XOR-swizzled LDS offset (shorts) for [row][32-short] tiles: 16B unit u ^= (row>>1)&3.
__device__ __forceinline__ int swz(int row, int u) {
    return (row << 5) + ((u ^ ((row >> 1) & 3)) << 3);
}

// async global->LDS, 16 B per lane; LDS dest = wave-uniform base + lane*16 (linear).
// Swizzle achieved by inverse-permuting the per-lane GLOBAL source (rule #21).
__device__ __forceinline__ void gload16(const unsigned short* g, unsigned short* l) {
    __builtin_amdgcn_global_load_lds(
        (const __attribute__((address_space(1))) void*)g,
        (__attribute__((address_space(3))) void*)l, 16, 0, 0);
}

// ---------- fp32 -> bf16 convert (n multiple of 4) ----------
__global__ __launch_bounds__(256)
void f2bf_kernel(const float* __restrict__ in, unsigned short* __restrict__ out, int n)
{
    int i = (blockIdx.x * 256 + threadIdx.x) * 4;
    if (i < n) {
        float4 v = *(const float4*)(in + i);
        ushort4 o;
        o.x = f2bf(v.x); o.y = f2bf(v.y); o.z = f2bf(v.z); o.w = f2bf(v.w);
        *(ushort4*)(out + i) = o;
    }
}

// ---------- Wvo[d,k] = sum_e cow[d,e]*cWv[e,k] (bf16), bvo[d] = cow[d,:].cbv + cob[d] ----------
__global__ __launch_bounds__(256)
void fold_wvo(const float* __restrict__ cow, const float* __restrict__ cWv,
              const float* __restrict__ cbv, const float* __restrict__ cob,
              unsigned short* __restrict__ Wvob, float* __restrict__ bvo)
{
    __shared__ float crow[DIM];
    __shared__ float red[256];
    const int d = blockIdx.x, t = threadIdx.x;
    float c0 = cow[d * DIM + t], c1 = cow[d * DIM + t + 256];
    crow[t] = c0; crow[t + 256] = c1;
    red[t] = c0 * cbv[t] + c1 * cbv[t + 256];
    __syncthreads();
    for (int s = 128; s > 0; s >>= 1) {
        if (t < s) red[t] += red[t + s];
        __syncthreads();
    }
    if (t == 0) bvo[d] = red[0] + cob[d];
    float a0 = 0.f, a1 = 0.f;
    for (int e = 0; e < DIM; e++) {
        float ce = crow[e];
        a0 += ce * cWv[e * DIM + t];
        a1 += ce * cWv[e * DIM + t + 256];
    }
    Wvob[d * DIM + t]       = f2bf(a0);
    Wvob[d * DIM + t + 256] = f2bf(a1);
}

// ---------- small fp32 tiled GEMM: C[M,N] = (A[M,K] @ W[N,K]^T + bias) * scale ----------
#define BKT 32
#define LDT 68
__global__ __launch_bounds__(256)
void gemm_bt_f32(const float* __restrict__ A, const float* __restrict__ W,
                 const float* __restrict__ bias, float* __restrict__ Co,
                 int M, int N, int K, float out_scale)
{
    __shared__ float As[BKT * LDT];
    __shared__ float Ws[BKT * LDT];
    const int tid = threadIdx.x;
    const int m0 = blockIdx.y << 6, n0 = blockIdx.x << 6;
    const int tx = tid & 15, ty = tid >> 4;
    float acc[4][4] = {};
    for (int k0 = 0; k0 < K; k0 += BKT) {
        #pragma unroll
        for (int i = 0; i < 2; i++) {
            int slot = tid + (i << 8);
            int r = slot >> 3, kq = slot & 7;
            float4 v = *(const float4*)(A + (size_t)(m0 + r) * K + k0 + (kq << 2));
            As[(kq*4+0)*LDT + r] = v.x; As[(kq*4+1)*LDT + r] = v.y;
            As[(kq*4+2)*LDT + r] = v.z; As[(kq*4+3)*LDT + r] = v.w;
            float4 w = *(const float4*)(W + (size_t)(n0 + r) * K + k0 + (kq << 2));
            Ws[(kq*4+0)*LDT + r] = w.x; Ws[(kq*4+1)*LDT + r] = w.y;
            Ws[(kq*4+2)*LDT + r] = w.z; Ws[(kq*4+3)*LDT + r] = w.w;
        }
        __syncthreads();
        #pragma unroll
        for (int kk = 0; kk < BKT; kk++) {
            float4 a = *(const float4*)(As + kk*LDT + ty*4);
            float4 w = *(const float4*)(Ws + kk*LDT + tx*4);
            acc[0][0] += a.x*w.x; acc[0][1] += a.x*w.y; acc[0][2] += a.x*w.z; acc[0][3] += a.x*w.w;
            acc[1][0] += a.y*w.x; acc[1][1] += a.y*w.y; acc[1][2] += a.y*w.z; acc[1][3] += a.y*w.w;
            acc[2][0] += a.z*w.x; acc[2][1] += a.z*w.y; acc[2][2] += a.z*w.z; acc[2][3] += a.z*w.w;
            acc[3][0] += a.w*w.x; acc[3][1] += a.w*w.y; acc[3][2] += a.w*w.z; acc[3][3] += a.w*w.w;
        }
        __syncthreads();
    }
    #pragma unroll
    for (int i = 0; i < 4; i++) {
        int mr = m0 + ty*4 + i;
        #pragma unroll
        for (int j = 0; j < 4; j++) {
            int n = n0 + tx*4 + j;
            float v = acc[i][j];
            if (bias) v += bias[n];
            Co[(size_t)mr * N + n] = v * out_scale;
        }
    }
}

// ---------- fp32 GEMM, B NOT transposed, bf16 PACKED output into q2pb ----------
// q2k = q2s @ cWk; row mr = l*64+b  ->  q2pb row b*16+l (l>=12 pad rows pre-zeroed).
__global__ __launch_bounds__(256)
void gemm_nt_q2p(const float* __restrict__ A, const float* __restrict__ W,
                 unsigned short* __restrict__ q2pb, int M, int N, int K)
{
    __shared__ float As[BKT * LDT];
    __shared__ float Ws[BKT * LDT];
    const int tid = threadIdx.x;
    const int m0 = blockIdx.y << 6, n0 = blockIdx.x << 6;
    const int tx = tid & 15, ty = tid >> 4;
    float acc[4][4] = {};
    for (int k0 = 0; k0 < K; k0 += BKT) {
        #pragma unroll
        for (int i = 0; i < 2; i++) {
            int slot = tid + (i << 8);
            int r = slot >> 3, kq = slot & 7;
            float4 v = *(const float4*)(A + (size_t)(m0 + r) * K + k0 + (kq << 2));
            As[(kq*4+0)*LDT + r] = v.x; As[(kq*4+1)*LDT + r] = v.y;
            As[(kq*4+2)*LDT + r] = v.z; As[(kq*4+3)*LDT + r] = v.w;
            int kr = slot >> 4, c4 = slot & 15;
            *(float4*)(Ws + kr*LDT + c4*4) =
                *(const float4*)(W + (size_t)(k0 + kr) * N + n0 + (c4 << 2));
        }
        __syncthreads();
        #pragma unroll
        for (int kk = 0; kk < BKT; kk++) {
            float4 a = *(const float4*)(As + kk*LDT + ty*4);
            float4 w = *(const float4*)(Ws + kk*LDT + tx*4);
            acc[0][0] += a.x*w.x; acc[0][1] += a.x*w.y; acc[0][2] += a.x*w.z; acc[0][3] += a.x*w.w;
            acc[1][0] += a.y*w.x; acc[1][1] += a.y*w.y; acc[1][2] += a.y*w.z; acc[1][3] += a.y*w.w;
            acc[2][0] += a.z*w.x; acc[2][1] += a.z*w.y; acc[2][2] += a.z*w.z; acc[2][3] += a.z*w.w;
            acc[3][0] += a.w*w.x; acc[3][1] += a.w*w.y; acc[3][2] += a.w*w.z; acc[3][3] += a.w*w.w;
        }
        __syncthreads();
    }
    #pragma unroll
    for (int i = 0; i < 4; i++) {
        int mr = m0 + ty*4 + i;
        int l = mr >> 6, b = mr & 63;
        ushort4 o;
        o.x = f2bf(acc[i][0]); o.y = f2bf(acc[i][1]);
        o.z = f2bf(acc[i][2]); o.w = f2bf(acc[i][3]);
        *(ushort4*)(q2pb + ((size_t)(b * 16 + l)) * DIM + n0 + tx * 4) = o;
    }
}

// ---------- self-attention over the 12-layer axis, one block per batch ----------
__global__ __launch_bounds__(256)
void attn_kernel(const float* __restrict__ qkv, float* __restrict__ ao)
{
    __shared__ float lq[L_IMG * DIM];
    __shared__ float lk[L_IMG * DIM];
    __shared__ float sc[L_IMG * L_IMG];
    __shared__ float sa[L_IMG * L_IMG];
    const int b = blockIdx.x, tid = threadIdx.x;
    for (int i = 0; i < 6; i++) {
        int slot = tid + (i << 8);
        int l = slot >> 7, e4 = slot & 127;
        const float* row = qkv + (size_t)(l * BATCH + b) * 1536;
        *(float4*)(lq + l*DIM + e4*4) = *(const float4*)(row + e4*4);
        *(float4*)(lk + l*DIM + e4*4) = *(const float4*)(row + DIM + e4*4);
    }
    __syncthreads();
    if (tid < 144) {
        int l = tid / 12, m = tid % 12;
        float a = 0.f;
        for (int d4 = 0; d4 < 128; d4++) {
            float4 q = *(const float4*)(lq + l*DIM + d4*4);
            float4 k = *(const float4*)(lk + m*DIM + d4*4);
            a += q.x*k.x + q.y*k.y + q.z*k.z + q.w*k.w;
        }
        sc[tid] = a * SCALEF;
    }
    __syncthreads();
    if (tid < 12) {
        float mx = -1e30f;
        for (int m = 0; m < 12; m++) mx = fmaxf(mx, sc[tid*12 + m]);
        float e[12], s = 0.f;
        for (int m = 0; m < 12; m++) { e[m] = __expf(sc[tid*12 + m] - mx); s += e[m]; }
        float inv = 1.f / s;
        for (int m = 0; m < 12; m++) sa[tid*12 + m] = e[m] * inv;
    }
    __syncthreads();
    for (int i = 0; i < 2; i++) {
        int e = tid + (i << 8);
        float vv[12];
        #pragma unroll
        for (int m = 0; m < 12; m++)
            vv[m] = qkv[(size_t)(m * BATCH + b) * 1536 + 1024 + e];
        #pragma unroll
        for (int l = 0; l < 12; l++) {
            float a = 0.f;
            #pragma unroll
            for (int m = 0; m < 12; m++) a += sa[l*12 + m] * vv[m];
            ao[(size_t)(l * BATCH + b) * DIM + e] = a;
        }
    }
}

// ---------- normalize image features (xs layer 11) ----------
__global__ __launch_bounds__(256)
void img_kernel(const float* __restrict__ xs, float* __restrict__ imgn)
{
    __shared__ float red[256];
    const int b = blockIdx.x, tid = threadIdx.x;
    const float* row = xs + (size_t)(11 * BATCH + b) * DIM;
    float v0 = row[tid], v1 = row[tid + 256];
    red[tid] = v0*v0 + v1*v1;
    __syncthreads();
    for (int s = 128; s > 0; s >>= 1) {
        if (tid < s) red[tid] += red[tid + s];
        __syncthreads();
    }
    float inv = rsqrtf(red[0]);
    imgn[b*DIM + tid]       = v0 * inv;
    imgn[b*DIM + tid + 256] = v1 * inv;
}

// ---------- MFMA GEMM: C[M,N] = A[M,K]@W[N,K]^T + bias ; 128x128 tile, BK=32 ----------
// Async global_load_lds staging, double-buffered. Fused n2 epilogue (optional).
// 1-D grid, XCD-grouped: new-id n -> orig=(n&7)*250+(n>>3); the 4 n-tiles of one
// m-tile get consecutive orig ids on the SAME XCD -> A-tile L2 reuse. Grid must be 2000.
template<typename OutT>
__global__ __launch_bounds__(256, 4)
void gemm_mfma(const unsigned short* __restrict__ A, const unsigned short* __restrict__ W,
               const float* __restrict__ bias, OutT* __restrict__ Co,
               int M, int N, float scale, float* __restrict__ n2)
{
    const int K = DIM;
    __shared__ __align__(16) unsigned short AsBuf[2][128 * 32];
    __shared__ __align__(16) unsigned short WsBuf[2][128 * 32];
    const int nb = blockIdx.x;
    const int orig = (nb & 7) * 250 + (nb >> 3);
    const int m0 = (orig >> 2) << 7, n0 = (orig & 3) << 7;
    const int tid = threadIdx.x;
    const int w = tid >> 6, lane = tid & 63;
    const int mt0 = (w & 1) * 4, nt0 = (w >> 1) * 4;
    const int r16 = lane & 15, kq = lane >> 4;
    const int row0 = (w << 5) + (lane >> 2), row1 = row0 + 16;
    const int sc0 = ((lane & 3) ^ ((row0 >> 1) & 3)) << 3;
    const int sc1 = ((lane & 3) ^ ((row1 >> 1) & 3)) << 3;
    const unsigned short* gA0 = A + (size_t)(m0 + row0) * K + sc0;
    const unsigned short* gA1 = A + (size_t)(m0 + row1) * K + sc1;
    const unsigned short* gW0 = W + (size_t)(n0 + row0) * K + sc0;
    const unsigned short* gW1 = W + (size_t)(n0 + row1) * K + sc1;
    const int lw = w << 10;
    int offa[4], offb[4];
    #pragma unroll
    for (int i = 0; i < 4; i++) {
        offa[i] = swz((mt0 + i) * 16 + r16, kq);
        offb[i] = swz((nt0 + i) * 16 + r16, kq);
    }
    f32x4 acc[4][4] = {};

    gload16(gA0, AsBuf[0] + lw);
    gload16(gA1, AsBuf[0] + lw + 512);
    gload16(gW0, WsBuf[0] + lw);
    gload16(gW1, WsBuf[0] + lw + 512);
    __syncthreads();

    #pragma unroll
    for (int t = 0; t < 16; t++) {
        const int cur = t & 1, nxt = cur ^ 1;
        if (t < 15) {
            const int ko = (t + 1) << 5;
            gload16(gA0 + ko, AsBuf[nxt] + lw);
            gload16(gA1 + ko, AsBuf[nxt] + lw + 512);
            gload16(gW0 + ko, WsBuf[nxt] + lw);
            gload16(gW1 + ko, WsBuf[nxt] + lw + 512);
        }
        bf16x8 af[4], bfr[4];
        #pragma unroll
        for (int i = 0; i < 4; i++) {
            af[i]  = *(const bf16x8*)(AsBuf[cur] + offa[i]);
            bfr[i] = *(const bf16x8*)(WsBuf[cur] + offb[i]);
        }
        #pragma unroll
        for (int i = 0; i < 4; i++)
            #pragma unroll
            for (int j = 0; j < 4; j++)
                acc[i][j] = __builtin_amdgcn_mfma_f32_16x16x32_bf16(af[i], bfr[j], acc[i][j], 0, 0, 0);
        if (t < 15) __syncthreads();
    }
    const int rbase = (lane >> 4) * 4;
    const int b0 = m0 / NCLS;
    const int splitrow = (b0 + 1) * NCLS;
    #pragma unroll
    for (int j = 0; j < 4; j++) {
        int gcol = n0 + (nt0 + j) * 16 + r16;
        float bv = bias ? bias[gcol] : 0.f;
        float s0 = 0.f, s1 = 0.f;
        #pragma unroll
        for (int i = 0; i < 4; i++)
            #pragma unroll
            for (int r = 0; r < 4; r++) {
                int grow = m0 + (mt0 + i) * 16 + rbase + r;
                float v = acc[i][j][r] * scale + bv;
                storeo(Co + (size_t)grow * N + gcol, v);
                if (n2) { if (grow < splitrow) s0 += v * v; else s1 += v * v; }
            }
        if (n2) {
            s0 += __shfl_xor(s0, 16, 64); s0 += __shfl_xor(s0, 32, 64);
            s1 += __shfl_xor(s1, 16, 64); s1 += __shfl_xor(s1, 32, 64);
            if (lane < 16) {
                atomicAdd(&n2[(size_t)b0 * N + gcol], s0);
                if (splitrow < m0 + 128) atomicAdd(&n2[(size_t)(b0 + 1) * N + gcol], s1);
            }
        }
    }
}

// ---------- fused scores + softmax(m) + sum_l: one block = (class c, 16 batches) ----------
// R8 known-good: 256 rows/block (16 b * 16, l>=12 zero-padded), wave = 64 rows x 96 cols
// (acc[4][6]). K-source is tfeb directly (cWk folded into query; k-bias cancels in
// softmax). Async global_load_lds staging; XCD-grouped 1-D grid.
__global__ __launch_bounds__(256, 3)
void fused_scores(const unsigned short* __restrict__ q2pb, const unsigned short* __restrict__ k2,
                  float* __restrict__ wout)
{
    __shared__ __align__(16) unsigned short AsBuf[2][256 * 32];  // 2 x 16384 B
    __shared__ __align__(16) unsigned short KsBuf[2][96 * 32];   // 2 x  6144 B
    const int bid = blockIdx.x;
    const int g8 = bid >> 5, r = bid & 31;
    const int c = g8 * 8 + (r & 7), bg = r >> 3;     // bg in 0..3, 16 batches each
    const int tid = threadIdx.x;
    const int m0 = bg << 8;
    const int w = tid >> 6, lane = tid & 63;
    const int r16 = lane & 15, kq = lane >> 4;
    const size_t kb = (size_t)c * NTM * DIM;
    const int arow = lane >> 2, aun = lane & 3;
    const unsigned short* gAs[4];
    #pragma unroll
    for (int s = 0; s < 4; s++) {
        int rw = (w << 6) + (s << 4) + arow;
        int scx = (aun ^ ((rw >> 1) & 3)) << 3;
        gAs[s] = q2pb + (size_t)(m0 + rw) * DIM + scx;
    }
    const int krow0 = (w << 5) + arow, krow1 = krow0 + 16;
    const int sk0 = (aun ^ ((krow0 >> 1) & 3)) << 3;
    const int sk1 = (aun ^ ((krow1 >> 1) & 3)) << 3;
    const unsigned short* gK0 = k2 + kb + (size_t)krow0 * DIM + sk0;
    const unsigned short* gK1 = k2 + kb + (size_t)krow1 * DIM + sk1;
    const bool kw = (w < 3);
    const int lwA = w << 11;
    const int lwK = w << 10;
    int offa[4], offk[6];
    #pragma unroll
    for (int i = 0; i < 4; i++) offa[i] = swz((w << 6) + i * 16 + r16, kq);
    #pragma unroll
    for (int j = 0; j < 6; j++) offk[j] = swz(j * 16 + r16, kq);
    f32x4 acc[4][6] = {};

    #pragma unroll
    for (int s = 0; s < 4; s++) gload16(gAs[s], AsBuf[0] + lwA + (s << 9));
    if (kw) {
        gload16(gK0, KsBuf[0] + lwK);
        gload16(gK1, KsBuf[0] + lwK + 512);
    }
    __syncthreads();

    #pragma unroll
    for (int t = 0; t < 16; t++) {
        const int cur = t & 1, nxt = cur ^ 1;
        if (t < 15) {
            const int ko = (t + 1) << 5;
            #pragma unroll
            for (int s = 0; s < 4; s++) gload16(gAs[s] + ko, AsBuf[nxt] + lwA + (s << 9));
            if (kw) {
                gload16(gK0 + ko, KsBuf[nxt] + lwK);
                gload16(gK1 + ko, KsBuf[nxt] + lwK + 512);
            }
        }
        bf16x8 af[4], bfr[6];
        #pragma unroll
        for (int i = 0; i < 4; i++)
            af[i] = *(const bf16x8*)(AsBuf[cur] + offa[i]);
        #pragma unroll
        for (int j = 0; j < 6; j++)
            bfr[j] = *(const bf16x8*)(KsBuf[cur] + offk[j]);
        __builtin_amdgcn_s_setprio(1);
        #pragma unroll
        for (int i = 0; i < 4; i++)
            #pragma unroll
            for (int j = 0; j < 6; j++)
                acc[i][j] = __builtin_amdgcn_mfma_f32_16x16x32_bf16(af[i], bfr[j], acc[i][j], 0, 0, 0);
        __builtin_amdgcn_s_setprio(0);
        if (t < 15) __syncthreads();
    }

    #pragma unroll
    for (int i = 0; i < 4; i++) {
        #pragma unroll
        for (int rr = 0; rr < 4; rr++) {
            float v0 = acc[i][0][rr], v1 = acc[i][1][rr], v2 = acc[i][2][rr];
            float v3 = acc[i][3][rr], v4 = acc[i][4][rr], v5 = acc[i][5][rr];
            float mx = fmaxf(fmaxf(fmaxf(v0, v1), fmaxf(v2, v3)), fmaxf(v4, v5));
            mx = fmaxf(mx, __shfl_xor(mx, 8, 64));
            float e0 = __expf(v0 - mx), e1 = __expf(v1 - mx), e2 = __expf(v2 - mx);
            float e3 = __expf(v3 - mx), e4 = __expf(v4 - mx), e5 = __expf(v5 - mx);
            float s = e0 + e1 + e2 + e3 + e4 + e5;
            s += __shfl_xor(s, 8, 64);
            float inv = 1.f / (96.f * s);
            acc[i][0][rr] = e0 * inv; acc[i][1][rr] = e1 * inv; acc[i][2][rr] = e2 * inv;
            acc[i][3][rr] = e3 * inv; acc[i][4][rr] = e4 * inv; acc[i][5][rr] = e5 * inv;
        }
    }

    const bool contrib = (lane >> 4) < 3;
    #pragma unroll
    for (int i = 0; i < 4; i++) {
        float s6[6];
        #pragma unroll
        for (int j = 0; j < 6; j++) {
            float t = contrib ? (acc[i][j][0] + acc[i][j][1] + acc[i][j][2] + acc[i][j][3]) : 0.f;
            t += __shfl_xor(t, 16, 64);
            t += __shfl_xor(t, 32, 64);
            s6[j] = t;
        }
        if (lane < 16) {
            const int b = bg * 16 + (w << 2) + i;
            float* dst = wout + ((size_t)(b * NCLS + c)) * NTM;
            #pragma unroll
            for (int j = 0; j < 6; j++)
                dst[j * 16 + r16] = s6[j];
        }
    }
}

// ---------- ctxraw via MFMA: one block = (class c, d-half h) ----------
// ctxraw[b,c,:] = w[b,c,:] @ tf[c]  ->  per block [64 b][96 tm] @ [96 tm][256 d].
// tf is [tm][d] (contraction dim outer) so the B-operand is built by an LDS
// transpose: tfT[d][tm] with tm-BLOCK XOR swizzle blk ^= ((d>>3)^d)&7 (keeps the
// 8-short k-chunks contiguous + 16B-aligned; breaks the 32-way write conflict).
// K = 96 = 3x32 exactly. A = bf16(w) staged in LDS [64][96].
__global__ __launch_bounds__(256, 2)
void ctx_mfma(const float* __restrict__ wbuf, const unsigned short* __restrict__ tfeb,
              unsigned short* __restrict__ ctxraw)
{
    __shared__ __align__(16) unsigned short tfT[256 * 128];  // 64 KB: [d][blk^s | tm&7]
    __shared__ __align__(16) unsigned short Aw[64 * 96];     // 12 KB: [b][tm]
    const int bid = blockIdx.x;
    const int c = bid >> 1, h = bid & 1;
    const int tid = threadIdx.x;
    const int w = tid >> 6, lane = tid & 63;
    const int r16 = lane & 15, kq = lane >> 4;

    // transpose-stage tf half-rows
    {
        const unsigned short* src = tfeb + (size_t)c * NTM * DIM + (h << 8);
        const int tmb = tid >> 5;            // 0..7
        const int d8 = (tid & 31) << 3;      // 0..248
        for (int p = 0; p < 12; p++) {
            int tm = p * 8 + tmb;
            bf16x8 v = *(const bf16x8*)(src + (size_t)tm * DIM + d8);
            #pragma unroll
            for (int i = 0; i < 8; i++) {
                int d = d8 + i;
                int blk = (tm >> 3) ^ (((d >> 3) ^ d) & 7);
                tfT[d * 128 + blk * 8 + (tm & 7)] = (unsigned short)v[i];
            }
        }
    }
    // stage A = bf16(w[b, c, tm])
    for (int p = 0; p < 24; p++) {
        int idx = (p << 8) + tid;            // 0..6143
        int b = idx / 96, tm = idx - b * 96;
        Aw[idx] = f2bf(wbuf[((size_t)(b * NCLS + c)) * NTM + tm]);
    }
    __syncthreads();

    f32x4 acc[4][4] = {};
    #pragma unroll
    for (int ks = 0; ks < 3; ks++) {
        bf16x8 af[4], bfr[4];
        #pragma unroll
        for (int mt = 0; mt < 4; mt++)
            af[mt] = *(const bf16x8*)(Aw + (mt * 16 + r16) * 96 + ks * 32 + kq * 8);
        #pragma unroll
        for (int nt = 0; nt < 4; nt++) {
            int d = (w << 6) + nt * 16 + r16;
            int blk = (ks * 4 + kq) ^ (((d >> 3) ^ d) & 7);
            bfr[nt] = *(const bf16x8*)(tfT + d * 128 + blk * 8);
        }
        #pragma unroll
        for (int mt = 0; mt < 4; mt++)
            #pragma unroll
            for (int nt = 0; nt < 4; nt++)
                acc[mt][nt] = __builtin_amdgcn_mfma_f32_16x16x32_bf16(af[mt], bfr[nt], acc[mt][nt], 0, 0, 0);
    }
    const int rbase = (lane >> 4) << 2;
    #pragma unroll
    for (int mt = 0; mt < 4; mt++)
        #pragma unroll
        for (int r = 0; r < 4; r++) {
            int b = mt * 16 + rbase + r;
            unsigned short* dst = ctxraw + ((size_t)(b * NCLS + c)) * DIM + (h << 8) + (w << 6) + r16;
            #pragma unroll
            for (int nt = 0; nt < 4; nt++)
                dst[nt * 16] = f2bf(acc[mt][nt][r]);
        }
}

// ---------- logits[b,c] = exp(ls) * sum_d imgn[b,d]/sqrt(n2[b,d]) * txt[b,c,d] ----------
__global__ __launch_bounds__(256)
void logits_kernel(const unsigned short* __restrict__ txt, const float* __restrict__ imgn,
                   const float* __restrict__ n2, const float* __restrict__ logit_scale,
                   float* __restrict__ out)
{
    __shared__ float lu[DIM];
    const int b = blockIdx.y, cg = blockIdx.x, tid = threadIdx.x;
    float els = expf(logit_scale[0]);
    lu[tid]       = els * imgn[b*DIM + tid]       * rsqrtf(n2[b*DIM + tid]);
    lu[tid + 256] = els * imgn[b*DIM + tid + 256] * rsqrtf(n2[b*DIM + tid + 256]);
    __syncthreads();
    int wave = tid >> 6, lane = tid & 63;
    int c = (cg << 2) + wave;
    const unsigned short* row = txt + (size_t)(b * NCLS + c) * DIM;
    ushort4 p0 = ((const ushort4*)row)[lane*2];
    ushort4 p1 = ((const ushort4*)row)[lane*2 + 1];
    int d0 = lane * 8;
    float s = bf2f(p0.x)*lu[d0]   + bf2f(p0.y)*lu[d0+1] + bf2f(p0.z)*lu[d0+2] + bf2f(p0.w)*lu[d0+3]
            + bf2f(p1.x)*lu[d0+4] + bf2f(p1.y)*lu[d0+5] + bf2f(p1.z)*lu[d0+6] + bf2f(p1.w)*lu[d0+7];
    #pragma unroll
    for (int off = 32; off > 0; off >>= 1) s += __shfl_down(s, off, 64);
    if (lane == 0) out[b*NCLS + c] = s;
}

extern "C" void kernel_launch(void* const* d_in, const int* in_sizes, int n_in,
                              void* d_out, int out_size, void* d_ws, size_t ws_size,
                              hipStream_t stream)
{
    const float* x   = (const float*)d_in[0];
    const float* tfe = (const float*)d_in[1];
    const float* siw = (const float*)d_in[2];
    const float* sib = (const float*)d_in[3];
    const float* sow = (const float*)d_in[4];
    const float* sob = (const float*)d_in[5];
    const float* ciw = (const float*)d_in[6];
    const float* cib = (const float*)d_in[7];
    const float* cow = (const float*)d_in[8];
    const float* cob = (const float*)d_in[9];
    const float* ls  = (const float*)d_in[10];
    float* out = (float*)d_out;

    char* p = (char*)d_ws;
    auto alloc = [&](size_t bytes) { char* r = p; p += (bytes + 255) & ~255ull; return r; };
    unsigned short* tfeb   = (unsigned short*)alloc((size_t)49152000 * 2);   // 98.3 MB
    unsigned short* ctxraw = (unsigned short*)alloc((size_t)BATCH * NCLS * DIM * 2);  // 65.5 MB
    float* wbuf            = (float*)alloc((size_t)BATCH * NCLS * NTM * 4);  // 24.6 MB
    float* qkv             = (float*)alloc((size_t)768 * 1536 * 4);
    float* ao              = (float*)alloc((size_t)768 * DIM * 4);
    float* xs              = (float*)alloc((size_t)768 * DIM * 4);
    float* q2s             = (float*)alloc((size_t)768 * DIM * 4);
    unsigned short* q2pb   = (unsigned short*)alloc((size_t)1024 * DIM * 2);
    unsigned short* Wvob   = (unsigned short*)alloc((size_t)DIM * DIM * 2);
    float* bvo             = (float*)alloc(DIM * 4);
    float* n2              = (float*)alloc(BATCH * DIM * 4);
    float* imgn            = (float*)alloc(BATCH * DIM * 4);
    unsigned short* txt    = tfeb;   // alias: tfeb dead after ctx_mfma; txt written after

    hipMemsetAsync(n2, 0, BATCH * DIM * 4, stream);
    hipMemsetAsync(q2pb, 0, (size_t)1024 * DIM * 2, stream);   // pad rows l>=12 stay zero

    // weight/text prep
    f2bf_kernel<<<48000, 256, 0, stream>>>(tfe, tfeb, 49152000);
    fold_wvo<<<512, 256, 0, stream>>>(cow, ciw + 1024*512, cib + 1024, cob, Wvob, bvo);

    // self-attn head (fp32, small)
    gemm_bt_f32<<<dim3(24, 12), 256, 0, stream>>>(x, siw, sib, qkv, 768, 1536, 512, 1.f);
    attn_kernel<<<64, 256, 0, stream>>>(qkv, ao);
    gemm_bt_f32<<<dim3(8, 12), 256, 0, stream>>>(ao, sow, sob, xs, 768, 512, 512, 1.f);
    img_kernel<<<64, 256, 0, stream>>>(xs, imgn);
    gemm_bt_f32<<<dim3(8, 12), 256, 0, stream>>>(xs, ciw, cib, q2s, 768, 512, 512, SCALEF);
    // fold cWk into query and write bf16 padded q2pb directly (k-bias cancels in softmax)
    gemm_nt_q2p<<<dim3(8, 12), 256, 0, stream>>>(q2s, ciw + 512*512, q2pb, 768, 512, 512);

    // fused scores+softmax -> w[b,c,96]  (K = raw text features; XCD-grouped 1-D grid)
    fused_scores<<<4000, 256, 0, stream>>>(q2pb, tfeb, wbuf);

    // ctxraw = w @ tf  (MFMA with in-LDS transpose of tf)
    ctx_mfma<<<2000, 256, 0, stream>>>(wbuf, tfeb, ctxraw);

    // txt = ctxraw @ Wvob^T + (bvo + cob)   (MFMA, 64000 rows; n2 fused; XCD-grouped)
    gemm_mfma<unsigned short><<<2000, 256, 0, stream>>>(
        ctxraw, Wvob, bvo, txt, 64000, 512, 1.f, n2);

    // logits
    logits_kernel<<<dim3(250, 64), 256, 0, stream>>>(txt, imgn, n2, ls, out);
}